// Round 1
// baseline (2037.854 us; speedup 1.0000x reference)
//
#include <hip/hip_runtime.h>
#include <stdint.h>

#define NPTS (96*96*96)          // 884736
#define EMPTY_KEY 0xFFFFFFFFFFFFFFFFull

__device__ __forceinline__ uint64_t mix64(uint64_t x){
  x ^= x >> 33; x *= 0xff51afd7ed558ccdULL;
  x ^= x >> 33; x *= 0xc4ceb9fe1a85ec53ULL;
  x ^= x >> 33; return x;
}

__device__ __forceinline__ int hfind(const unsigned long long* __restrict__ hkeys,
                                     const int* __restrict__ hidx,
                                     unsigned long long key, unsigned int tmask){
  unsigned int slot = (unsigned int)mix64(key) & tmask;
  while (true){
    unsigned long long k = hkeys[slot];
    if (k == key) return hidx[slot];
    if (k == EMPTY_KEY) return -1;
    slot = (slot + 1) & tmask;
  }
}

// Phase 1: per-point lattice math, hash-insert the 5 simplex-vertex keys,
// record slot + barycentric weight per (point, vertex).
__global__ void k_build(const float* __restrict__ image,
                        unsigned long long* __restrict__ hkeys,
                        unsigned int tmask,
                        int* __restrict__ slots,
                        float* __restrict__ baryo)
{
  int n = blockIdx.x * blockDim.x + threadIdx.x;
  if (n >= NPTS) return;
  int x = n % 96, y = (n / 96) % 96, z = n / (96 * 96);

  // feats * scale (scale computed in double, cast to float, matching jnp.asarray(..., f32))
  float cf[4];
  cf[0] = ((float)z / 5.0f) * 2.8867513459481287f;   // inv_std/sqrt(2)
  cf[1] = ((float)y / 5.0f) * 1.6666666666666667f;   // inv_std/sqrt(6)
  cf[2] = ((float)x / 5.0f) * 1.1785113019775793f;   // inv_std/sqrt(12)
  cf[3] = (image[n] / 0.25f) * 0.9128709291752769f;  // inv_std/sqrt(20)

  float elev[5];
  float sm = 0.f;
  #pragma unroll
  for (int i = 4; i >= 1; --i){ float c = cf[i-1]; elev[i] = sm - (float)i * c; sm += c; }
  elev[0] = sm;

  float rem0[5]; float sumrd_f = 0.f;
  #pragma unroll
  for (int i = 0; i < 5; i++){ float rd = rintf(elev[i] / 5.0f); rem0[i] = rd * 5.0f; sumrd_f += rd; }
  int sum_rd = (int)sumrd_f;

  float diff[5];
  #pragma unroll
  for (int i = 0; i < 5; i++) diff[i] = elev[i] - rem0[i];

  int rank[5];
  #pragma unroll
  for (int i = 0; i < 5; i++){
    int r = 0;
    #pragma unroll
    for (int j = 0; j < 5; j++){
      r += (diff[j] > diff[i] || (diff[j] == diff[i] && j < i)) ? 1 : 0;
    }
    rank[i] = r + sum_rd;
  }
  #pragma unroll
  for (int i = 0; i < 5; i++){
    if (rank[i] < 0)      { rank[i] += 5; rem0[i] += 5.0f; }
    else if (rank[i] > 4) { rank[i] -= 5; rem0[i] -= 5.0f; }
  }

  float b[6] = {0.f,0.f,0.f,0.f,0.f,0.f};
  #pragma unroll
  for (int i = 0; i < 5; i++){
    float v = (elev[i] - rem0[i]) / 5.0f;
    b[4 - rank[i]] += v;
    b[5 - rank[i]] -= v;
  }
  b[0] += 1.0f + b[5];

  int rem0i[4];
  #pragma unroll
  for (int i = 0; i < 4; i++) rem0i[i] = (int)rem0[i];

  #pragma unroll
  for (int r = 0; r < 5; r++){
    long long enc = 0;
    #pragma unroll
    for (int i = 0; i < 4; i++){
      int ki = rem0i[i] + (rank[i] < 5 - r ? r : r - 5);
      enc = enc * 8192 + (long long)(ki + 4096);
    }
    unsigned long long key = (unsigned long long)enc;
    unsigned int slot = (unsigned int)mix64(key) & tmask;
    while (true){
      unsigned long long k = hkeys[slot];
      if (k == key) break;
      if (k == EMPTY_KEY){
        unsigned long long prev = atomicCAS(&hkeys[slot], EMPTY_KEY, key);
        if (prev == EMPTY_KEY || prev == key) break;
      }
      slot = (slot + 1) & tmask;
    }
    slots[n * 5 + r] = (int)slot;
    baryo[n * 5 + r] = b[r];
  }
}

// Phase 2: compact occupied hash slots -> dense lattice indices
__global__ void k_compact(const unsigned long long* __restrict__ hkeys,
                          int* __restrict__ hidx,
                          unsigned long long* __restrict__ lkeys,
                          int tsize, int Mmax, int* __restrict__ counter)
{
  int s = blockIdx.x * blockDim.x + threadIdx.x;
  if (s >= tsize) return;
  unsigned long long k = hkeys[s];
  if (k == EMPTY_KEY) return;   // hidx stays -1 (memset 0xFF)
  int m = atomicAdd(counter, 1);
  if (m < Mmax){ hidx[s] = m; lkeys[m] = k; }
}

// Phase 3: splat values into lattice
__global__ void k_splat(const float* __restrict__ input_,
                        const int* __restrict__ slots,
                        const float* __restrict__ bary,
                        const int* __restrict__ hidx,
                        float* __restrict__ vals, int Mmax)
{
  int n = blockIdx.x * blockDim.x + threadIdx.x;
  if (n >= NPTS) return;
  float q[5];
  #pragma unroll
  for (int c = 0; c < 4; c++) q[c] = input_[c * NPTS + n];
  q[4] = 1.0f;
  #pragma unroll
  for (int r = 0; r < 5; r++){
    int m = hidx[slots[n * 5 + r]];
    if (m < 0 || m >= Mmax) continue;
    float w = bary[n * 5 + r];
    #pragma unroll
    for (int c = 0; c < 5; c++)
      atomicAdd(&vals[m * 5 + c], w * q[c]);
  }
}

// Phase 4: one blur pass along one lattice direction (encoded-key delta)
__global__ void k_blur(const unsigned long long* __restrict__ hkeys,
                       const int* __restrict__ hidx,
                       const unsigned long long* __restrict__ lkeys,
                       const float* __restrict__ vin,
                       float* __restrict__ vout,
                       const int* __restrict__ counterM,
                       unsigned int tmask, long long delta, int Mmax)
{
  int m = blockIdx.x * blockDim.x + threadIdx.x;
  int M = *counterM; if (M > Mmax) M = Mmax;
  if (m >= M) return;
  unsigned long long key = lkeys[m];
  int p1 = hfind(hkeys, hidx, (unsigned long long)((long long)key + delta), tmask);
  int p2 = hfind(hkeys, hidx, (unsigned long long)((long long)key - delta), tmask);
  #pragma unroll
  for (int c = 0; c < 5; c++){
    float n1 = (p1 >= 0) ? vin[p1 * 5 + c] : 0.0f;
    float n2 = (p2 >= 0) ? vin[p2 * 5 + c] : 0.0f;
    vout[m * 5 + c] = 0.5f * vin[m * 5 + c] + 0.25f * (n1 + n2);
  }
}

// Phase 5: slice + normalize
__global__ void k_slice(const int* __restrict__ slots,
                        const float* __restrict__ bary,
                        const int* __restrict__ hidx,
                        const float* __restrict__ vals,
                        float* __restrict__ out, int Mmax)
{
  int n = blockIdx.x * blockDim.x + threadIdx.x;
  if (n >= NPTS) return;
  float s[5] = {0.f,0.f,0.f,0.f,0.f};
  #pragma unroll
  for (int r = 0; r < 5; r++){
    int m = hidx[slots[n * 5 + r]];
    float w = bary[n * 5 + r];
    if (m >= 0 && m < Mmax){
      #pragma unroll
      for (int c = 0; c < 5; c++) s[c] += w * vals[m * 5 + c];
    }
  }
  float denom = s[4] + 2.2204460492503131e-16f;
  #pragma unroll
  for (int c = 0; c < 4; c++) out[c * NPTS + n] = s[c] / denom;
}

extern "C" void kernel_launch(void* const* d_in, const int* in_sizes, int n_in,
                              void* d_out, int out_size, void* d_ws, size_t ws_size,
                              hipStream_t stream)
{
  const float* input_ = (const float*)d_in[0];
  const float* image  = (const float*)d_in[1];
  float* out = (float*)d_out;
  char* ws = (char*)d_ws;

  const size_t NP = (size_t)NPTS;

  // Workspace layout: pick largest config that fits ws_size.
  struct Cfg { int tb; size_t M; };
  const Cfg cfgs[5] = { {23, NP * 5}, {23, 3200000}, {22, 3000000}, {22, 2000000}, {21, 1500000} };
  int tbits = 21; size_t Mmax = 1500000;
  size_t off_hkeys = 0, off_hidx = 0, off_cnt = 0, off_slots = 0, off_bary = 0,
         off_lkeys = 0, off_vA = 0, off_vB = 0;
  for (int i = 0; i < 5; i++){
    size_t T = (size_t)1 << cfgs[i].tb; size_t M = cfgs[i].M;
    size_t o = 0;
    off_hkeys = o; o += T * 8;
    off_hidx  = o; o += T * 4;
    off_cnt   = o; o += 256;
    off_slots = o; o += NP * 5 * 4;
    off_bary  = o; o += NP * 5 * 4;
    off_lkeys = o; o += M * 8;
    off_vA    = o; o += M * 5 * 4;
    off_vB    = o; o += M * 5 * 4;
    tbits = cfgs[i].tb; Mmax = M;
    if (o <= ws_size) break;
  }
  size_t T = (size_t)1 << tbits;
  unsigned int tmask = (unsigned int)(T - 1);

  unsigned long long* hkeys = (unsigned long long*)(ws + off_hkeys);
  int*                hidx  = (int*)(ws + off_hidx);
  int*                cnt   = (int*)(ws + off_cnt);
  int*                slots = (int*)(ws + off_slots);
  float*              bary  = (float*)(ws + off_bary);
  unsigned long long* lkeys = (unsigned long long*)(ws + off_lkeys);
  float*              valsA = (float*)(ws + off_vA);
  float*              valsB = (float*)(ws + off_vB);

  // hkeys + hidx are adjacent: one 0xFF memset covers both (EMPTY_KEY / -1)
  hipMemsetAsync(ws + off_hkeys, 0xFF, T * 8 + T * 4, stream);
  hipMemsetAsync(ws + off_cnt, 0, 256, stream);
  hipMemsetAsync(ws + off_vA, 0, Mmax * 5 * 4, stream);

  const int NB = (NPTS + 255) / 256;

  k_build<<<NB, 256, 0, stream>>>(image, hkeys, tmask, slots, bary);
  k_compact<<<(int)(T / 256), 256, 0, stream>>>(hkeys, hidx, lkeys, (int)T, (int)Mmax, cnt);
  k_splat<<<NB, 256, 0, stream>>>(input_, slots, bary, hidx, valsA, (int)Mmax);

  // Lattice-direction deltas in encoded-key space (base 8192 positional fields)
  const long long P3 = 1ll << 39, P2 = 1ll << 26, P1 = 1ll << 13, P0 = 1ll;
  const long long Dall = P3 + P2 + P1 + P0;
  const long long deltas[5] = { Dall - 5*P3, Dall - 5*P2, Dall - 5*P1, Dall - 5*P0, Dall };

  float* vin = valsA; float* vout = valsB;
  const int MB = (int)((Mmax + 255) / 256);
  for (int j = 0; j < 5; j++){
    k_blur<<<MB, 256, 0, stream>>>(hkeys, hidx, lkeys, vin, vout, cnt, tmask, deltas[j], (int)Mmax);
    float* t = vin; vin = vout; vout = t;
  }

  k_slice<<<NB, 256, 0, stream>>>(slots, bary, hidx, vin, out, (int)Mmax);
}

// Round 2
// 2014.868 us; speedup vs baseline: 1.0114x; 1.0114x over previous
//
#include <hip/hip_runtime.h>
#include <stdint.h>

#define NPTS (96*96*96)          // 884736
#define NP5  (NPTS*5)            // 4423680 worst-case unique keys
#define EMPTY_KEY 0xFFFFFFFFFFFFFFFFull

__device__ __forceinline__ uint64_t mix64(uint64_t x){
  x ^= x >> 33; x *= 0xff51afd7ed558ccdULL;
  x ^= x >> 33; x *= 0xc4ceb9fe1a85ec53ULL;
  x ^= x >> 33; return x;
}

__device__ __forceinline__ int hfind(const unsigned long long* __restrict__ hkeys,
                                     const int* __restrict__ hidx,
                                     unsigned long long key, unsigned int tmask){
  unsigned int slot = (unsigned int)mix64(key) & tmask;
  while (true){
    unsigned long long k = hkeys[slot];
    if (k == key) return hidx[slot];
    if (k == EMPTY_KEY) return -1;
    slot = (slot + 1) & tmask;
  }
}

// Phase 1: per-point lattice math, hash-insert the 5 simplex-vertex keys,
// record slot + barycentric weight per (point, vertex).
__global__ void k_build(const float* __restrict__ image,
                        unsigned long long* __restrict__ hkeys,
                        unsigned int tmask,
                        int* __restrict__ slots,
                        float* __restrict__ baryo)
{
  int n = blockIdx.x * blockDim.x + threadIdx.x;
  if (n >= NPTS) return;
  int x = n % 96, y = (n / 96) % 96, z = n / (96 * 96);

  float cf[4];
  cf[0] = ((float)z / 5.0f) * 2.8867513459481287f;   // inv_std/sqrt(2)
  cf[1] = ((float)y / 5.0f) * 1.6666666666666667f;   // inv_std/sqrt(6)
  cf[2] = ((float)x / 5.0f) * 1.1785113019775793f;   // inv_std/sqrt(12)
  cf[3] = (image[n] / 0.25f) * 0.9128709291752769f;  // inv_std/sqrt(20)

  float elev[5];
  float sm = 0.f;
  #pragma unroll
  for (int i = 4; i >= 1; --i){ float c = cf[i-1]; elev[i] = sm - (float)i * c; sm += c; }
  elev[0] = sm;

  float rem0[5]; float sumrd_f = 0.f;
  #pragma unroll
  for (int i = 0; i < 5; i++){ float rd = rintf(elev[i] / 5.0f); rem0[i] = rd * 5.0f; sumrd_f += rd; }
  int sum_rd = (int)sumrd_f;

  float diff[5];
  #pragma unroll
  for (int i = 0; i < 5; i++) diff[i] = elev[i] - rem0[i];

  int rank[5];
  #pragma unroll
  for (int i = 0; i < 5; i++){
    int r = 0;
    #pragma unroll
    for (int j = 0; j < 5; j++){
      r += (diff[j] > diff[i] || (diff[j] == diff[i] && j < i)) ? 1 : 0;
    }
    rank[i] = r + sum_rd;
  }
  #pragma unroll
  for (int i = 0; i < 5; i++){
    if (rank[i] < 0)      { rank[i] += 5; rem0[i] += 5.0f; }
    else if (rank[i] > 4) { rank[i] -= 5; rem0[i] -= 5.0f; }
  }

  float b[6] = {0.f,0.f,0.f,0.f,0.f,0.f};
  #pragma unroll
  for (int i = 0; i < 5; i++){
    float v = (elev[i] - rem0[i]) / 5.0f;
    b[4 - rank[i]] += v;
    b[5 - rank[i]] -= v;
  }
  b[0] += 1.0f + b[5];

  int rem0i[4];
  #pragma unroll
  for (int i = 0; i < 4; i++) rem0i[i] = (int)rem0[i];

  #pragma unroll
  for (int r = 0; r < 5; r++){
    long long enc = 0;
    #pragma unroll
    for (int i = 0; i < 4; i++){
      int ki = rem0i[i] + (rank[i] < 5 - r ? r : r - 5);
      enc = enc * 8192 + (long long)(ki + 4096);
    }
    unsigned long long key = (unsigned long long)enc;
    unsigned int slot = (unsigned int)mix64(key) & tmask;
    while (true){
      unsigned long long k = hkeys[slot];
      if (k == key) break;
      if (k == EMPTY_KEY){
        unsigned long long prev = atomicCAS(&hkeys[slot], EMPTY_KEY, key);
        if (prev == EMPTY_KEY || prev == key) break;
      }
      slot = (slot + 1) & tmask;
    }
    slots[n * 5 + r] = (int)slot;
    baryo[n * 5 + r] = b[r];
  }
}

// Phase 2: compact occupied hash slots -> dense lattice indices
__global__ void k_compact(const unsigned long long* __restrict__ hkeys,
                          int* __restrict__ hidx,
                          unsigned long long* __restrict__ lkeys,
                          int tsize, int Mmax, int* __restrict__ counter)
{
  int s = blockIdx.x * blockDim.x + threadIdx.x;
  if (s >= tsize) return;
  unsigned long long k = hkeys[s];
  if (k == EMPTY_KEY) return;   // hidx stays -1 (memset 0xFF)
  int m = atomicAdd(counter, 1);
  if (m < Mmax){ hidx[s] = m; lkeys[m] = k; }
}

// Zero the replica accumulators: R * Mact * 5 floats (Mact read from counter)
__global__ void k_zero(float* __restrict__ rep, const int* __restrict__ counterM,
                       int Mmax, int R)
{
  int Mact = *counterM; if (Mact > Mmax) Mact = Mmax;
  long long total = (long long)R * Mact * 5;
  long long stride = (long long)gridDim.x * blockDim.x;
  for (long long i = (long long)blockIdx.x * blockDim.x + threadIdx.x; i < total; i += stride)
    rep[i] = 0.0f;
}

// Phase 3: splat values into R replicated accumulators, channel-staggered
__global__ void k_splat(const float* __restrict__ input_,
                        const int* __restrict__ slots,
                        const float* __restrict__ bary,
                        const int* __restrict__ hidx,
                        float* __restrict__ repbuf,
                        const int* __restrict__ counterM,
                        int Mmax, int R)
{
  int n = blockIdx.x * blockDim.x + threadIdx.x;
  if (n >= NPTS) return;
  int Mact = *counterM; if (Mact > Mmax) Mact = Mmax;
  int rep = (blockIdx.x ^ (threadIdx.x >> 6)) & (R - 1);
  float* __restrict__ base = repbuf + (size_t)rep * (size_t)Mact * 5;

  float q[5];
  #pragma unroll
  for (int c = 0; c < 4; c++) q[c] = input_[c * NPTS + n];
  q[4] = 1.0f;
  int c0 = n % 5;

  #pragma unroll
  for (int r = 0; r < 5; r++){
    int m = hidx[slots[n * 5 + r]];
    if (m < 0 || m >= Mact) continue;
    float w = bary[n * 5 + r];
    size_t mb = (size_t)m * 5;
    #define S(c) atomicAdd(&base[mb + (c)], w * q[(c)]);
    switch (c0){
      case 0: S(0) S(1) S(2) S(3) S(4) break;
      case 1: S(1) S(2) S(3) S(4) S(0) break;
      case 2: S(2) S(3) S(4) S(0) S(1) break;
      case 3: S(3) S(4) S(0) S(1) S(2) break;
      default: S(4) S(0) S(1) S(2) S(3) break;
    }
    #undef S
  }
}

// Sum replicas -> valsA
__global__ void k_reduce(const float* __restrict__ repbuf,
                         float* __restrict__ valsA,
                         const int* __restrict__ counterM,
                         int Mmax, int R)
{
  int Mact = *counterM; if (Mact > Mmax) Mact = Mmax;
  long long tot = (long long)Mact * 5;
  long long stride = (long long)gridDim.x * blockDim.x;
  for (long long i = (long long)blockIdx.x * blockDim.x + threadIdx.x; i < tot; i += stride){
    float s = 0.f;
    for (int r = 0; r < R; r++) s += repbuf[(long long)r * tot + i];
    valsA[i] = s;
  }
}

// Phase 4: one blur pass along one lattice direction (encoded-key delta)
__global__ void k_blur(const unsigned long long* __restrict__ hkeys,
                       const int* __restrict__ hidx,
                       const unsigned long long* __restrict__ lkeys,
                       const float* __restrict__ vin,
                       float* __restrict__ vout,
                       const int* __restrict__ counterM,
                       unsigned int tmask, long long delta, int Mmax)
{
  int m = blockIdx.x * blockDim.x + threadIdx.x;
  int M = *counterM; if (M > Mmax) M = Mmax;
  if (m >= M) return;
  unsigned long long key = lkeys[m];
  int p1 = hfind(hkeys, hidx, (unsigned long long)((long long)key + delta), tmask);
  int p2 = hfind(hkeys, hidx, (unsigned long long)((long long)key - delta), tmask);
  #pragma unroll
  for (int c = 0; c < 5; c++){
    float n1 = (p1 >= 0) ? vin[p1 * 5 + c] : 0.0f;
    float n2 = (p2 >= 0) ? vin[p2 * 5 + c] : 0.0f;
    vout[m * 5 + c] = 0.5f * vin[m * 5 + c] + 0.25f * (n1 + n2);
  }
}

// Phase 5: slice + normalize
__global__ void k_slice(const int* __restrict__ slots,
                        const float* __restrict__ bary,
                        const int* __restrict__ hidx,
                        const float* __restrict__ vals,
                        float* __restrict__ out,
                        const int* __restrict__ counterM, int Mmax)
{
  int n = blockIdx.x * blockDim.x + threadIdx.x;
  if (n >= NPTS) return;
  int Mact = *counterM; if (Mact > Mmax) Mact = Mmax;
  float s[5] = {0.f,0.f,0.f,0.f,0.f};
  #pragma unroll
  for (int r = 0; r < 5; r++){
    int m = hidx[slots[n * 5 + r]];
    float w = bary[n * 5 + r];
    if (m >= 0 && m < Mact){
      #pragma unroll
      for (int c = 0; c < 5; c++) s[c] += w * vals[m * 5 + c];
    }
  }
  float denom = s[4] + 2.2204460492503131e-16f;
  #pragma unroll
  for (int c = 0; c < 4; c++) out[c * NPTS + n] = s[c] / denom;
}

extern "C" void kernel_launch(void* const* d_in, const int* in_sizes, int n_in,
                              void* d_out, int out_size, void* d_ws, size_t ws_size,
                              hipStream_t stream)
{
  const float* input_ = (const float*)d_in[0];
  const float* image  = (const float*)d_in[1];
  float* out = (float*)d_out;
  char* ws = (char*)d_ws;

  // Workspace ladder: prefer full-safety table (2^23 slots covers NP5 worst-case
  // uniques at load 0.53) + max replicas; degrade R, then M/table if tight.
  struct Cfg { int tb; size_t M; int R; };
  const Cfg cfgs[] = {
    {23, (size_t)NP5, 8}, {23, (size_t)NP5, 4}, {23, (size_t)NP5, 2}, {23, (size_t)NP5, 1},
    {23, 3200000, 1}, {22, 2000000, 1}, {21, 1500000, 1}
  };
  const int NCFG = sizeof(cfgs) / sizeof(cfgs[0]);

  int tbits = 21; size_t Mmax = 1500000; int R = 1;
  size_t off_hkeys = 0, off_hidx = 0, off_cnt = 0, off_slots = 0, off_bary = 0,
         off_lkeys = 0, off_vA = 0, off_rep = 0;
  for (int i = 0; i < NCFG; i++){
    size_t T = (size_t)1 << cfgs[i].tb; size_t M = cfgs[i].M; int r = cfgs[i].R;
    size_t o = 0;
    off_hkeys = o; o += T * 8;
    off_hidx  = o; o += T * 4;
    off_cnt   = o; o += 256;
    off_slots = o; o += (size_t)NP5 * 4;
    off_bary  = o; o += (size_t)NP5 * 4;
    off_lkeys = o; o += M * 8;
    off_vA    = o; o += M * 5 * 4;
    off_rep   = o; o += (size_t)r * M * 5 * 4;   // replicas; reused as blur pong
    tbits = cfgs[i].tb; Mmax = M; R = r;
    if (o <= ws_size) break;
  }
  size_t T = (size_t)1 << tbits;
  unsigned int tmask = (unsigned int)(T - 1);

  unsigned long long* hkeys = (unsigned long long*)(ws + off_hkeys);
  int*                hidx  = (int*)(ws + off_hidx);
  int*                cnt   = (int*)(ws + off_cnt);
  int*                slots = (int*)(ws + off_slots);
  float*              bary  = (float*)(ws + off_bary);
  unsigned long long* lkeys = (unsigned long long*)(ws + off_lkeys);
  float*              valsA = (float*)(ws + off_vA);
  float*              repbuf = (R > 1) ? (float*)(ws + off_rep) : valsA;
  float*              valsB = (float*)(ws + off_rep);  // pong buffer (replicas dead by then)

  // hkeys + hidx adjacent: one 0xFF memset covers both (EMPTY_KEY / -1)
  hipMemsetAsync(ws + off_hkeys, 0xFF, T * 8 + T * 4, stream);
  hipMemsetAsync(ws + off_cnt, 0, 256, stream);

  const int NB = (NPTS + 255) / 256;

  k_build<<<NB, 256, 0, stream>>>(image, hkeys, tmask, slots, bary);
  k_compact<<<(int)(T / 256), 256, 0, stream>>>(hkeys, hidx, lkeys, (int)T, (int)Mmax, cnt);
  k_zero<<<4096, 256, 0, stream>>>(repbuf, cnt, (int)Mmax, R);
  k_splat<<<NB, 256, 0, stream>>>(input_, slots, bary, hidx, repbuf, cnt, (int)Mmax, R);
  if (R > 1)
    k_reduce<<<4096, 256, 0, stream>>>(repbuf, valsA, cnt, (int)Mmax, R);

  // Lattice-direction deltas in encoded-key space (base 8192 positional fields)
  const long long P3 = 1ll << 39, P2 = 1ll << 26, P1 = 1ll << 13, P0 = 1ll;
  const long long Dall = P3 + P2 + P1 + P0;
  const long long deltas[5] = { Dall - 5*P3, Dall - 5*P2, Dall - 5*P1, Dall - 5*P0, Dall };

  float* vin = valsA; float* vout = valsB;
  const int MB = (int)((Mmax + 255) / 256);
  for (int j = 0; j < 5; j++){
    k_blur<<<MB, 256, 0, stream>>>(hkeys, hidx, lkeys, vin, vout, cnt, tmask, deltas[j], (int)Mmax);
    float* t = vin; vin = vout; vout = t;
  }

  k_slice<<<NB, 256, 0, stream>>>(slots, bary, hidx, vin, out, cnt, (int)Mmax);
}

// Round 3
// 1119.226 us; speedup vs baseline: 1.8208x; 1.8002x over previous
//
#include <hip/hip_runtime.h>
#include <stdint.h>

#define NPTS (96*96*96)          // 884736
#define NP5  (NPTS*5)            // 4423680 worst-case unique keys
#define EMPTY_KEY 0xFFFFFFFFFFFFFFFFull

__device__ __forceinline__ uint64_t mix64(uint64_t x){
  x ^= x >> 33; x *= 0xff51afd7ed558ccdULL;
  x ^= x >> 33; x *= 0xc4ceb9fe1a85ec53ULL;
  x ^= x >> 33; return x;
}

__device__ __forceinline__ int hfind(const unsigned long long* __restrict__ hkeys,
                                     const int* __restrict__ hidx,
                                     unsigned long long key, unsigned int tmask){
  unsigned int slot = (unsigned int)mix64(key) & tmask;
  while (true){
    unsigned long long k = hkeys[slot];
    if (k == key) return hidx[slot];
    if (k == EMPTY_KEY) return -1;
    slot = (slot + 1) & tmask;
  }
}

// Pack input_ channels into float4 per point (one 16B read per gather hop)
__global__ void k_qpack(const float* __restrict__ input_, float4* __restrict__ qp)
{
  int n = blockIdx.x * blockDim.x + threadIdx.x;
  if (n >= NPTS) return;
  qp[n] = make_float4(input_[n], input_[NPTS + n], input_[2 * NPTS + n], input_[3 * NPTS + n]);
}

// Phase 1: per-point lattice math, hash-insert the 5 simplex-vertex keys,
// record slot + bary per (point, vertex), and thread each pair onto the
// slot's linked list (head/next) for the gather-splat.
__global__ void k_build(const float* __restrict__ image,
                        unsigned long long* __restrict__ hkeys,
                        unsigned int tmask,
                        int* __restrict__ slots,
                        float* __restrict__ baryo,
                        int* __restrict__ head,
                        int* __restrict__ nexte)
{
  int n = blockIdx.x * blockDim.x + threadIdx.x;
  if (n >= NPTS) return;
  int x = n % 96, y = (n / 96) % 96, z = n / (96 * 96);

  float cf[4];
  cf[0] = ((float)z / 5.0f) * 2.8867513459481287f;   // inv_std/sqrt(2)
  cf[1] = ((float)y / 5.0f) * 1.6666666666666667f;   // inv_std/sqrt(6)
  cf[2] = ((float)x / 5.0f) * 1.1785113019775793f;   // inv_std/sqrt(12)
  cf[3] = (image[n] / 0.25f) * 0.9128709291752769f;  // inv_std/sqrt(20)

  float elev[5];
  float sm = 0.f;
  #pragma unroll
  for (int i = 4; i >= 1; --i){ float c = cf[i-1]; elev[i] = sm - (float)i * c; sm += c; }
  elev[0] = sm;

  float rem0[5]; float sumrd_f = 0.f;
  #pragma unroll
  for (int i = 0; i < 5; i++){ float rd = rintf(elev[i] / 5.0f); rem0[i] = rd * 5.0f; sumrd_f += rd; }
  int sum_rd = (int)sumrd_f;

  float diff[5];
  #pragma unroll
  for (int i = 0; i < 5; i++) diff[i] = elev[i] - rem0[i];

  int rank[5];
  #pragma unroll
  for (int i = 0; i < 5; i++){
    int r = 0;
    #pragma unroll
    for (int j = 0; j < 5; j++){
      r += (diff[j] > diff[i] || (diff[j] == diff[i] && j < i)) ? 1 : 0;
    }
    rank[i] = r + sum_rd;
  }
  #pragma unroll
  for (int i = 0; i < 5; i++){
    if (rank[i] < 0)      { rank[i] += 5; rem0[i] += 5.0f; }
    else if (rank[i] > 4) { rank[i] -= 5; rem0[i] -= 5.0f; }
  }

  float b[6] = {0.f,0.f,0.f,0.f,0.f,0.f};
  #pragma unroll
  for (int i = 0; i < 5; i++){
    float v = (elev[i] - rem0[i]) / 5.0f;
    b[4 - rank[i]] += v;
    b[5 - rank[i]] -= v;
  }
  b[0] += 1.0f + b[5];

  int rem0i[4];
  #pragma unroll
  for (int i = 0; i < 4; i++) rem0i[i] = (int)rem0[i];

  #pragma unroll
  for (int r = 0; r < 5; r++){
    long long enc = 0;
    #pragma unroll
    for (int i = 0; i < 4; i++){
      int ki = rem0i[i] + (rank[i] < 5 - r ? r : r - 5);
      enc = enc * 8192 + (long long)(ki + 4096);
    }
    unsigned long long key = (unsigned long long)enc;
    unsigned int slot = (unsigned int)mix64(key) & tmask;
    while (true){
      unsigned long long k = hkeys[slot];
      if (k == key) break;
      if (k == EMPTY_KEY){
        unsigned long long prev = atomicCAS(&hkeys[slot], EMPTY_KEY, key);
        if (prev == EMPTY_KEY || prev == key) break;
      }
      slot = (slot + 1) & tmask;
    }
    int e = n * 5 + r;
    slots[e] = (int)slot;
    baryo[e] = b[r];
    int old = atomicExch(&head[slot], e);
    nexte[e] = old;   // safe: gather runs in a later kernel (kernel boundary syncs)
  }
}

// Phase 2: compact occupied hash slots -> dense lattice indices
__global__ void k_compact(const unsigned long long* __restrict__ hkeys,
                          int* __restrict__ hidx,
                          unsigned long long* __restrict__ lkeys,
                          int tsize, int Mmax, int* __restrict__ counter)
{
  int s = blockIdx.x * blockDim.x + threadIdx.x;
  if (s >= tsize) return;
  unsigned long long k = hkeys[s];
  if (k == EMPTY_KEY) return;   // hidx stays -1 (memset 0xFF)
  int m = atomicAdd(counter, 1);
  if (m < Mmax){ hidx[s] = m; lkeys[m] = k; }
}

// Phase 3: gather-splat — one thread per occupied slot walks its contributor
// chain and writes the vertex's 5 accumulated channels once. Zero atomics.
__global__ void k_gather(const int* __restrict__ head,
                         const int* __restrict__ hidx,
                         const int* __restrict__ nexte,
                         const float* __restrict__ bary,
                         const float4* __restrict__ qp,
                         float* __restrict__ vals,
                         int tsize, int Mmax)
{
  int s = blockIdx.x * blockDim.x + threadIdx.x;
  if (s >= tsize) return;
  int e = head[s];
  if (e < 0) return;
  int m = hidx[s];
  if (m < 0 || m >= Mmax) return;
  float s0 = 0.f, s1 = 0.f, s2 = 0.f, s3 = 0.f, s4 = 0.f;
  while (e >= 0){
    float w = bary[e];
    float4 q = qp[e / 5];
    s0 += w * q.x; s1 += w * q.y; s2 += w * q.z; s3 += w * q.w; s4 += w;
    e = nexte[e];
  }
  float* v = vals + (size_t)m * 5;
  v[0] = s0; v[1] = s1; v[2] = s2; v[3] = s3; v[4] = s4;
}

// Phase 4: one blur pass along one lattice direction (encoded-key delta)
__global__ void k_blur(const unsigned long long* __restrict__ hkeys,
                       const int* __restrict__ hidx,
                       const unsigned long long* __restrict__ lkeys,
                       const float* __restrict__ vin,
                       float* __restrict__ vout,
                       const int* __restrict__ counterM,
                       unsigned int tmask, long long delta, int Mmax)
{
  int m = blockIdx.x * blockDim.x + threadIdx.x;
  int M = *counterM; if (M > Mmax) M = Mmax;
  if (m >= M) return;
  unsigned long long key = lkeys[m];
  int p1 = hfind(hkeys, hidx, (unsigned long long)((long long)key + delta), tmask);
  int p2 = hfind(hkeys, hidx, (unsigned long long)((long long)key - delta), tmask);
  #pragma unroll
  for (int c = 0; c < 5; c++){
    float n1 = (p1 >= 0) ? vin[p1 * 5 + c] : 0.0f;
    float n2 = (p2 >= 0) ? vin[p2 * 5 + c] : 0.0f;
    vout[m * 5 + c] = 0.5f * vin[m * 5 + c] + 0.25f * (n1 + n2);
  }
}

// Phase 5: slice + normalize
__global__ void k_slice(const int* __restrict__ slots,
                        const float* __restrict__ bary,
                        const int* __restrict__ hidx,
                        const float* __restrict__ vals,
                        float* __restrict__ out,
                        const int* __restrict__ counterM, int Mmax)
{
  int n = blockIdx.x * blockDim.x + threadIdx.x;
  if (n >= NPTS) return;
  int Mact = *counterM; if (Mact > Mmax) Mact = Mmax;
  float s[5] = {0.f,0.f,0.f,0.f,0.f};
  #pragma unroll
  for (int r = 0; r < 5; r++){
    int m = hidx[slots[n * 5 + r]];
    float w = bary[n * 5 + r];
    if (m >= 0 && m < Mact){
      #pragma unroll
      for (int c = 0; c < 5; c++) s[c] += w * vals[m * 5 + c];
    }
  }
  float denom = s[4] + 2.2204460492503131e-16f;
  #pragma unroll
  for (int c = 0; c < 4; c++) out[c * NPTS + n] = s[c] / denom;
}

extern "C" void kernel_launch(void* const* d_in, const int* in_sizes, int n_in,
                              void* d_out, int out_size, void* d_ws, size_t ws_size,
                              hipStream_t stream)
{
  const float* input_ = (const float*)d_in[0];
  const float* image  = (const float*)d_in[1];
  float* out = (float*)d_out;
  char* ws = (char*)d_ws;

  // Workspace ladder: prefer full-safety table (2^23 slots covers NP5 worst-case
  // uniques at load 0.53); degrade table / M caps if scratch is tight.
  struct Cfg { int tb; size_t M; };
  const Cfg cfgs[] = {
    {23, (size_t)NP5}, {23, 3200000}, {22, 3000000}, {22, 2000000},
    {21, 1500000}, {20, 1000000}
  };
  const int NCFG = sizeof(cfgs) / sizeof(cfgs[0]);

  int tbits = 20; size_t Mmax = 1000000;
  size_t off_hkeys = 0, off_hidx = 0, off_head = 0, off_cnt = 0, off_slots = 0,
         off_bary = 0, off_next = 0, off_lkeys = 0, off_qp = 0, off_vA = 0, off_vB = 0;
  for (int i = 0; i < NCFG; i++){
    size_t T = (size_t)1 << cfgs[i].tb; size_t M = cfgs[i].M;
    size_t o = 0;
    off_hkeys = o; o += T * 8;
    off_hidx  = o; o += T * 4;
    off_head  = o; o += T * 4;          // adjacent: one 0xFF memset covers hkeys..head
    off_cnt   = o; o += 256;
    off_slots = o; o += (size_t)NP5 * 4;
    off_bary  = o; o += (size_t)NP5 * 4;
    off_next  = o; o += (size_t)NP5 * 4;
    off_lkeys = o; o += M * 8;
    off_qp    = o; o += (size_t)NPTS * 16;
    off_vA    = o; o += M * 5 * 4;
    off_vB    = o; o += M * 5 * 4;
    tbits = cfgs[i].tb; Mmax = M;
    if (o <= ws_size) break;
  }
  size_t T = (size_t)1 << tbits;
  unsigned int tmask = (unsigned int)(T - 1);

  unsigned long long* hkeys = (unsigned long long*)(ws + off_hkeys);
  int*                hidx  = (int*)(ws + off_hidx);
  int*                head  = (int*)(ws + off_head);
  int*                cnt   = (int*)(ws + off_cnt);
  int*                slots = (int*)(ws + off_slots);
  float*              bary  = (float*)(ws + off_bary);
  int*                nexte = (int*)(ws + off_next);
  unsigned long long* lkeys = (unsigned long long*)(ws + off_lkeys);
  float4*             qp    = (float4*)(ws + off_qp);
  float*              valsA = (float*)(ws + off_vA);
  float*              valsB = (float*)(ws + off_vB);

  // hkeys + hidx + head adjacent: one 0xFF memset (EMPTY_KEY / -1 / -1)
  hipMemsetAsync(ws + off_hkeys, 0xFF, T * 8 + T * 4 + T * 4, stream);
  hipMemsetAsync(ws + off_cnt, 0, 256, stream);

  const int NB = (NPTS + 255) / 256;
  const int TB = (int)((T + 255) / 256);

  k_qpack<<<NB, 256, 0, stream>>>(input_, qp);
  k_build<<<NB, 256, 0, stream>>>(image, hkeys, tmask, slots, bary, head, nexte);
  k_compact<<<TB, 256, 0, stream>>>(hkeys, hidx, lkeys, (int)T, (int)Mmax, cnt);
  k_gather<<<TB, 256, 0, stream>>>(head, hidx, nexte, bary, qp, valsA, (int)T, (int)Mmax);

  // Lattice-direction deltas in encoded-key space (base 8192 positional fields)
  const long long P3 = 1ll << 39, P2 = 1ll << 26, P1 = 1ll << 13, P0 = 1ll;
  const long long Dall = P3 + P2 + P1 + P0;
  const long long deltas[5] = { Dall - 5*P3, Dall - 5*P2, Dall - 5*P1, Dall - 5*P0, Dall };

  float* vin = valsA; float* vout = valsB;
  const int MB = (int)((Mmax + 255) / 256);
  for (int j = 0; j < 5; j++){
    k_blur<<<MB, 256, 0, stream>>>(hkeys, hidx, lkeys, vin, vout, cnt, tmask, deltas[j], (int)Mmax);
    float* t = vin; vin = vout; vout = t;
  }

  k_slice<<<NB, 256, 0, stream>>>(slots, bary, hidx, vin, out, cnt, (int)Mmax);
}

// Round 4
// 568.962 us; speedup vs baseline: 3.5817x; 1.9671x over previous
//
#include <hip/hip_runtime.h>
#include <stdint.h>

#define NPTS (96*96*96)          // 884736
#define NP5  (NPTS*5)            // 4423680 worst-case unique keys
#define EMPTY_KEY 0xFFFFFFFFFFFFFFFFull

__device__ __forceinline__ uint64_t mix64(uint64_t x){
  x ^= x >> 33; x *= 0xff51afd7ed558ccdULL;
  x ^= x >> 33; x *= 0xc4ceb9fe1a85ec53ULL;
  x ^= x >> 33; return x;
}

__device__ __forceinline__ int hfind(const unsigned long long* __restrict__ hkeys,
                                     const int* __restrict__ hidx,
                                     unsigned long long key, unsigned int tmask){
  unsigned int slot = (unsigned int)mix64(key) & tmask;
  while (true){
    unsigned long long k = hkeys[slot];
    if (k == key) return hidx[slot];
    if (k == EMPTY_KEY) return -1;
    slot = (slot + 1) & tmask;
  }
}

// Pack input_ channels into float4 per point (one 16B read per gather hop)
__global__ void k_qpack(const float* __restrict__ input_, float4* __restrict__ qp)
{
  int n = blockIdx.x * blockDim.x + threadIdx.x;
  if (n >= NPTS) return;
  qp[n] = make_float4(input_[n], input_[NPTS + n], input_[2 * NPTS + n], input_[3 * NPTS + n]);
}

// Phase 1: lattice math, hash-insert, dense-index assignment at insert time
// (CAS winner grabs m from the counter -> no separate compaction scan),
// and linked-list threading for the gather-splat.
__global__ void k_build(const float* __restrict__ image,
                        unsigned long long* __restrict__ hkeys,
                        unsigned int tmask,
                        int* __restrict__ slots,
                        float* __restrict__ baryo,
                        int* __restrict__ head,
                        int* __restrict__ nexte,
                        int* __restrict__ hidx,
                        unsigned long long* __restrict__ lkeys,
                        int* __restrict__ lslot,
                        int* __restrict__ cnt,
                        int Mmax)
{
  int n = blockIdx.x * blockDim.x + threadIdx.x;
  if (n >= NPTS) return;
  int x = n % 96, y = (n / 96) % 96, z = n / (96 * 96);

  float cf[4];
  cf[0] = ((float)z / 5.0f) * 2.8867513459481287f;   // inv_std/sqrt(2)
  cf[1] = ((float)y / 5.0f) * 1.6666666666666667f;   // inv_std/sqrt(6)
  cf[2] = ((float)x / 5.0f) * 1.1785113019775793f;   // inv_std/sqrt(12)
  cf[3] = (image[n] / 0.25f) * 0.9128709291752769f;  // inv_std/sqrt(20)

  float elev[5];
  float sm = 0.f;
  #pragma unroll
  for (int i = 4; i >= 1; --i){ float c = cf[i-1]; elev[i] = sm - (float)i * c; sm += c; }
  elev[0] = sm;

  float rem0[5]; float sumrd_f = 0.f;
  #pragma unroll
  for (int i = 0; i < 5; i++){ float rd = rintf(elev[i] / 5.0f); rem0[i] = rd * 5.0f; sumrd_f += rd; }
  int sum_rd = (int)sumrd_f;

  float diff[5];
  #pragma unroll
  for (int i = 0; i < 5; i++) diff[i] = elev[i] - rem0[i];

  int rank[5];
  #pragma unroll
  for (int i = 0; i < 5; i++){
    int r = 0;
    #pragma unroll
    for (int j = 0; j < 5; j++){
      r += (diff[j] > diff[i] || (diff[j] == diff[i] && j < i)) ? 1 : 0;
    }
    rank[i] = r + sum_rd;
  }
  #pragma unroll
  for (int i = 0; i < 5; i++){
    if (rank[i] < 0)      { rank[i] += 5; rem0[i] += 5.0f; }
    else if (rank[i] > 4) { rank[i] -= 5; rem0[i] -= 5.0f; }
  }

  float b[6] = {0.f,0.f,0.f,0.f,0.f,0.f};
  #pragma unroll
  for (int i = 0; i < 5; i++){
    float v = (elev[i] - rem0[i]) / 5.0f;
    b[4 - rank[i]] += v;
    b[5 - rank[i]] -= v;
  }
  b[0] += 1.0f + b[5];

  int rem0i[4];
  #pragma unroll
  for (int i = 0; i < 4; i++) rem0i[i] = (int)rem0[i];

  #pragma unroll
  for (int r = 0; r < 5; r++){
    long long enc = 0;
    #pragma unroll
    for (int i = 0; i < 4; i++){
      int ki = rem0i[i] + (rank[i] < 5 - r ? r : r - 5);
      enc = enc * 8192 + (long long)(ki + 4096);
    }
    unsigned long long key = (unsigned long long)enc;
    unsigned int slot = (unsigned int)mix64(key) & tmask;
    bool won = false;
    while (true){
      unsigned long long k = hkeys[slot];
      if (k == key) break;
      if (k == EMPTY_KEY){
        unsigned long long prev = atomicCAS(&hkeys[slot], EMPTY_KEY, key);
        if (prev == EMPTY_KEY){ won = true; break; }
        if (prev == key) break;
      }
      slot = (slot + 1) & tmask;
    }
    if (won){
      int m = atomicAdd(cnt, 1);       // divergent; LLVM atomic-optimizer wave-aggregates
      if (m < Mmax){ hidx[slot] = m; lkeys[m] = key; lslot[m] = (int)slot; }
    }
    int e = n * 5 + r;
    slots[e] = (int)slot;
    baryo[e] = b[r];
    int old = atomicExch(&head[slot], e);
    nexte[e] = old;   // safe: gather runs in a later kernel
  }
}

// Phase 2: gather-splat — one thread per lattice vertex walks its contributor
// chain and writes the vertex's 5 accumulated channels once. Zero atomics.
__global__ void k_gather(const int* __restrict__ lslot,
                         const int* __restrict__ head,
                         const int* __restrict__ nexte,
                         const float* __restrict__ bary,
                         const float4* __restrict__ qp,
                         float* __restrict__ vals,
                         const int* __restrict__ counterM, int Mmax)
{
  int m = blockIdx.x * blockDim.x + threadIdx.x;
  int M = *counterM; if (M > Mmax) M = Mmax;
  if (m >= M) return;
  int e = head[lslot[m]];
  float s0 = 0.f, s1 = 0.f, s2 = 0.f, s3 = 0.f, s4 = 0.f;
  while (e >= 0){
    float w = bary[e];
    float4 q = qp[e / 5];
    s0 += w * q.x; s1 += w * q.y; s2 += w * q.z; s3 += w * q.w; s4 += w;
    e = nexte[e];
  }
  float* v = vals + (size_t)m * 5;
  v[0] = s0; v[1] = s1; v[2] = s2; v[3] = s3; v[4] = s4;
}

// Phase 3: precompute neighbor dense-indices for all 5 lattice directions.
// 10 independent probes per vertex -> good memory-level parallelism.
__global__ void k_adj(const unsigned long long* __restrict__ hkeys,
                      const int* __restrict__ hidx,
                      const unsigned long long* __restrict__ lkeys,
                      int* __restrict__ nbr,
                      const int* __restrict__ counterM,
                      unsigned int tmask, int Mmax,
                      long long d0, long long d1, long long d2, long long d3, long long d4)
{
  int m = blockIdx.x * blockDim.x + threadIdx.x;
  int M = *counterM; if (M > Mmax) M = Mmax;
  if (m >= M) return;
  unsigned long long key = lkeys[m];
  long long dd[5] = {d0, d1, d2, d3, d4};
  #pragma unroll
  for (int j = 0; j < 5; j++){
    nbr[(size_t)m * 10 + 2*j]     = hfind(hkeys, hidx, (unsigned long long)((long long)key + dd[j]), tmask);
    nbr[(size_t)m * 10 + 2*j + 1] = hfind(hkeys, hidx, (unsigned long long)((long long)key - dd[j]), tmask);
  }
}

// Phase 4a: blur pass using precomputed neighbor table (pure gather)
__global__ void k_blur_adj(const int* __restrict__ nbr,
                           const float* __restrict__ vin,
                           float* __restrict__ vout,
                           const int* __restrict__ counterM,
                           int joff, int Mmax)
{
  int m = blockIdx.x * blockDim.x + threadIdx.x;
  int M = *counterM; if (M > Mmax) M = Mmax;
  if (m >= M) return;
  int p1 = nbr[(size_t)m * 10 + joff];
  int p2 = nbr[(size_t)m * 10 + joff + 1];
  #pragma unroll
  for (int c = 0; c < 5; c++){
    float n1 = (p1 >= 0) ? vin[p1 * 5 + c] : 0.0f;
    float n2 = (p2 >= 0) ? vin[p2 * 5 + c] : 0.0f;
    vout[m * 5 + c] = 0.5f * vin[m * 5 + c] + 0.25f * (n1 + n2);
  }
}

// Phase 4b: fallback blur with inline hash probes (if nbr doesn't fit in ws)
__global__ void k_blur(const unsigned long long* __restrict__ hkeys,
                       const int* __restrict__ hidx,
                       const unsigned long long* __restrict__ lkeys,
                       const float* __restrict__ vin,
                       float* __restrict__ vout,
                       const int* __restrict__ counterM,
                       unsigned int tmask, long long delta, int Mmax)
{
  int m = blockIdx.x * blockDim.x + threadIdx.x;
  int M = *counterM; if (M > Mmax) M = Mmax;
  if (m >= M) return;
  unsigned long long key = lkeys[m];
  int p1 = hfind(hkeys, hidx, (unsigned long long)((long long)key + delta), tmask);
  int p2 = hfind(hkeys, hidx, (unsigned long long)((long long)key - delta), tmask);
  #pragma unroll
  for (int c = 0; c < 5; c++){
    float n1 = (p1 >= 0) ? vin[p1 * 5 + c] : 0.0f;
    float n2 = (p2 >= 0) ? vin[p2 * 5 + c] : 0.0f;
    vout[m * 5 + c] = 0.5f * vin[m * 5 + c] + 0.25f * (n1 + n2);
  }
}

// Phase 5: slice + normalize
__global__ void k_slice(const int* __restrict__ slots,
                        const float* __restrict__ bary,
                        const int* __restrict__ hidx,
                        const float* __restrict__ vals,
                        float* __restrict__ out,
                        const int* __restrict__ counterM, int Mmax)
{
  int n = blockIdx.x * blockDim.x + threadIdx.x;
  if (n >= NPTS) return;
  int Mact = *counterM; if (Mact > Mmax) Mact = Mmax;
  float s[5] = {0.f,0.f,0.f,0.f,0.f};
  #pragma unroll
  for (int r = 0; r < 5; r++){
    int m = hidx[slots[n * 5 + r]];
    float w = bary[n * 5 + r];
    if (m >= 0 && m < Mact){
      #pragma unroll
      for (int c = 0; c < 5; c++) s[c] += w * vals[m * 5 + c];
    }
  }
  float denom = s[4] + 2.2204460492503131e-16f;
  #pragma unroll
  for (int c = 0; c < 4; c++) out[c * NPTS + n] = s[c] / denom;
}

extern "C" void kernel_launch(void* const* d_in, const int* in_sizes, int n_in,
                              void* d_out, int out_size, void* d_ws, size_t ws_size,
                              hipStream_t stream)
{
  const float* input_ = (const float*)d_in[0];
  const float* image  = (const float*)d_in[1];
  float* out = (float*)d_out;
  char* ws = (char*)d_ws;

  // Workspace ladder: prefer 2^23 table (covers NP5 worst-case uniques at load
  // 0.53) + neighbor table; degrade adj, then table / M caps if scratch tight.
  struct Cfg { int tb; size_t M; int adj; };
  const Cfg cfgs[] = {
    {23, (size_t)NP5, 1}, {23, (size_t)NP5, 0},
    {23, 3200000, 1}, {23, 3200000, 0},
    {22, 2000000, 1}, {22, 2000000, 0},
    {21, 1500000, 0}, {20, 1000000, 0}
  };
  const int NCFG = sizeof(cfgs) / sizeof(cfgs[0]);

  int tbits = 20; size_t Mmax = 1000000; int useAdj = 0;
  size_t off_hkeys = 0, off_hidx = 0, off_head = 0, off_cnt = 0, off_slots = 0,
         off_bary = 0, off_next = 0, off_lkeys = 0, off_lslot = 0, off_qp = 0,
         off_vA = 0, off_vB = 0, off_nbr = 0;
  for (int i = 0; i < NCFG; i++){
    size_t T = (size_t)1 << cfgs[i].tb; size_t M = cfgs[i].M; int a = cfgs[i].adj;
    size_t o = 0;
    off_hkeys = o; o += T * 8;
    off_hidx  = o; o += T * 4;
    off_head  = o; o += T * 4;          // adjacent: one 0xFF memset covers hkeys..head
    off_cnt   = o; o += 256;
    off_slots = o; o += (size_t)NP5 * 4;
    off_bary  = o; o += (size_t)NP5 * 4;
    off_next  = o; o += (size_t)NP5 * 4;
    off_lkeys = o; o += M * 8;
    off_lslot = o; o += M * 4;
    off_qp    = o; o += (size_t)NPTS * 16;
    off_vA    = o; o += M * 5 * 4;
    off_vB    = o; o += M * 5 * 4;
    off_nbr   = o; o += a ? (M * 10 * 4) : 0;
    tbits = cfgs[i].tb; Mmax = M; useAdj = a;
    if (o <= ws_size) break;
  }
  size_t T = (size_t)1 << tbits;
  unsigned int tmask = (unsigned int)(T - 1);

  unsigned long long* hkeys = (unsigned long long*)(ws + off_hkeys);
  int*                hidx  = (int*)(ws + off_hidx);
  int*                head  = (int*)(ws + off_head);
  int*                cnt   = (int*)(ws + off_cnt);
  int*                slots = (int*)(ws + off_slots);
  float*              bary  = (float*)(ws + off_bary);
  int*                nexte = (int*)(ws + off_next);
  unsigned long long* lkeys = (unsigned long long*)(ws + off_lkeys);
  int*                lslot = (int*)(ws + off_lslot);
  float4*             qp    = (float4*)(ws + off_qp);
  float*              valsA = (float*)(ws + off_vA);
  float*              valsB = (float*)(ws + off_vB);
  int*                nbr   = (int*)(ws + off_nbr);

  // hkeys + hidx + head adjacent: one 0xFF memset (EMPTY_KEY / -1 / -1)
  hipMemsetAsync(ws + off_hkeys, 0xFF, T * 8 + T * 4 + T * 4, stream);
  hipMemsetAsync(ws + off_cnt, 0, 256, stream);

  const int NB = (NPTS + 255) / 256;
  const int MB = (int)((Mmax + 255) / 256);

  k_qpack<<<NB, 256, 0, stream>>>(input_, qp);
  k_build<<<NB, 256, 0, stream>>>(image, hkeys, tmask, slots, bary, head, nexte,
                                  hidx, lkeys, lslot, cnt, (int)Mmax);
  k_gather<<<MB, 256, 0, stream>>>(lslot, head, nexte, bary, qp, valsA, cnt, (int)Mmax);

  // Lattice-direction deltas in encoded-key space (base 8192 positional fields)
  const long long P3 = 1ll << 39, P2 = 1ll << 26, P1 = 1ll << 13, P0 = 1ll;
  const long long Dall = P3 + P2 + P1 + P0;
  const long long deltas[5] = { Dall - 5*P3, Dall - 5*P2, Dall - 5*P1, Dall - 5*P0, Dall };

  float* vin = valsA; float* vout = valsB;
  if (useAdj){
    k_adj<<<MB, 256, 0, stream>>>(hkeys, hidx, lkeys, nbr, cnt, tmask, (int)Mmax,
                                  deltas[0], deltas[1], deltas[2], deltas[3], deltas[4]);
    for (int j = 0; j < 5; j++){
      k_blur_adj<<<MB, 256, 0, stream>>>(nbr, vin, vout, cnt, 2 * j, (int)Mmax);
      float* t = vin; vin = vout; vout = t;
    }
  } else {
    for (int j = 0; j < 5; j++){
      k_blur<<<MB, 256, 0, stream>>>(hkeys, hidx, lkeys, vin, vout, cnt, tmask, deltas[j], (int)Mmax);
      float* t = vin; vin = vout; vout = t;
    }
  }

  k_slice<<<NB, 256, 0, stream>>>(slots, bary, hidx, vin, out, cnt, (int)Mmax);
}

// Round 5
// 498.551 us; speedup vs baseline: 4.0876x; 1.1412x over previous
//
#include <hip/hip_runtime.h>
#include <stdint.h>

#define NPTS (96*96*96)          // 884736
#define NP5  (NPTS*5)            // 4423680 entries (point,vertex)
#define EMPTY_KEY 0xFFFFFFFFFFFFFFFFull

// Dense lattice grid (derived via interval arithmetic from the fixed input
// domain: z,y,x in [0,95], image in [0,1); includes rank-adjust, r-offset,
// blur-neighbor padding, and +/-2 safety margin):
//   q0 in [-3,25], q1 in [-14,14], q2 in [-16,8], q3 in [-17,3]
#define GD1 33
#define GD2 29
#define GD3 25
#define GO0 5
#define GO1 16
#define GO2 18
#define GO3 19
#define GS3 5
#define GS2 (GD3*GS3)      // 125
#define GS1 (GD2*GS2)      // 3625
#define GS0 (GD1*GS1)      // 119625
#define GCELLS (31*GS0)    // 3708375
#define GCELLS1 (GCELLS+1) // + trash cell for (never-expected) OOB
#define GSSUM (GS0+GS1+GS2+GS3)  // 123380

struct BN { float w; int next; };   // bary weight + chain link, 8B

__device__ __forceinline__ uint64_t mix64(uint64_t x){
  x ^= x >> 33; x *= 0xff51afd7ed558ccdULL;
  x ^= x >> 33; x *= 0xc4ceb9fe1a85ec53ULL;
  x ^= x >> 33; return x;
}

__device__ __forceinline__ int hfind(const unsigned long long* __restrict__ hkeys,
                                     const int* __restrict__ hidx,
                                     unsigned long long key, unsigned int tmask){
  unsigned int slot = (unsigned int)mix64(key) & tmask;
  while (true){
    unsigned long long k = hkeys[slot];
    if (k == key) return hidx[slot];
    if (k == EMPTY_KEY) return -1;
    slot = (slot + 1) & tmask;
  }
}

// Pack input_ channels into float4 per point
__global__ void k_qpack(const float* __restrict__ input_, float4* __restrict__ qp)
{
  int n = blockIdx.x * blockDim.x + threadIdx.x;
  if (n >= NPTS) return;
  qp[n] = make_float4(input_[n], input_[NPTS + n], input_[2 * NPTS + n], input_[3 * NPTS + n]);
}

// Shared per-point lattice math macro body producing rank[5], rem0i[4], b[5-ish]
#define LATTICE_MATH(n)                                                        \
  int x = n % 96, y = (n / 96) % 96, z = n / (96 * 96);                        \
  float cf[4];                                                                 \
  cf[0] = ((float)z / 5.0f) * 2.8867513459481287f;                             \
  cf[1] = ((float)y / 5.0f) * 1.6666666666666667f;                             \
  cf[2] = ((float)x / 5.0f) * 1.1785113019775793f;                             \
  cf[3] = (image[n] / 0.25f) * 0.9128709291752769f;                            \
  float elev[5];                                                               \
  float sm = 0.f;                                                              \
  _Pragma("unroll")                                                            \
  for (int i = 4; i >= 1; --i){ float c = cf[i-1]; elev[i] = sm - (float)i * c; sm += c; } \
  elev[0] = sm;                                                                \
  float rem0[5]; float sumrd_f = 0.f;                                          \
  _Pragma("unroll")                                                            \
  for (int i = 0; i < 5; i++){ float rd = rintf(elev[i] / 5.0f); rem0[i] = rd * 5.0f; sumrd_f += rd; } \
  int sum_rd = (int)sumrd_f;                                                   \
  float diff[5];                                                               \
  _Pragma("unroll")                                                            \
  for (int i = 0; i < 5; i++) diff[i] = elev[i] - rem0[i];                     \
  int rank[5];                                                                 \
  _Pragma("unroll")                                                            \
  for (int i = 0; i < 5; i++){                                                 \
    int r = 0;                                                                 \
    _Pragma("unroll")                                                          \
    for (int j = 0; j < 5; j++){                                               \
      r += (diff[j] > diff[i] || (diff[j] == diff[i] && j < i)) ? 1 : 0;       \
    }                                                                          \
    rank[i] = r + sum_rd;                                                      \
  }                                                                            \
  _Pragma("unroll")                                                            \
  for (int i = 0; i < 5; i++){                                                 \
    if (rank[i] < 0)      { rank[i] += 5; rem0[i] += 5.0f; }                   \
    else if (rank[i] > 4) { rank[i] -= 5; rem0[i] -= 5.0f; }                   \
  }                                                                            \
  float b[6] = {0.f,0.f,0.f,0.f,0.f,0.f};                                      \
  _Pragma("unroll")                                                            \
  for (int i = 0; i < 5; i++){                                                 \
    float v = (elev[i] - rem0[i]) / 5.0f;                                      \
    b[4 - rank[i]] += v;                                                       \
    b[5 - rank[i]] -= v;                                                       \
  }                                                                            \
  b[0] += 1.0f + b[5];                                                         \
  int rem0i[4];                                                                \
  _Pragma("unroll")                                                            \
  for (int i = 0; i < 4; i++) rem0i[i] = (int)rem0[i];

// ============================ DENSE-GRID PATH ============================

// Phase 1: lattice math + direct cell addressing + chain inversion (exch only)
__global__ void k_build_d(const float* __restrict__ image,
                          int* __restrict__ head,
                          int* __restrict__ slots,
                          BN* __restrict__ bnext)
{
  int n = blockIdx.x * blockDim.x + threadIdx.x;
  if (n >= NPTS) return;
  LATTICE_MATH(n)

  // key coord = 5*q + r; q = rem0i/5 - (offset is r-5 ? 1 : 0)
  int d0 = rem0i[0] / 5, d1 = rem0i[1] / 5, d2 = rem0i[2] / 5, d3 = rem0i[3] / 5;

  #pragma unroll
  for (int r = 0; r < 5; r++){
    int q0 = d0 - (rank[0] < 5 - r ? 0 : 1) + GO0;
    int q1 = d1 - (rank[1] < 5 - r ? 0 : 1) + GO1;
    int q2 = d2 - (rank[2] < 5 - r ? 0 : 1) + GO2;
    int q3 = d3 - (rank[3] < 5 - r ? 0 : 1) + GO3;
    int cell = (((q0 * GD1 + q1) * GD2 + q2) * GD3 + q3) * 5 + r;
    if ((unsigned)cell >= (unsigned)GCELLS) cell = GCELLS;  // trash (never expected)
    int e = n * 5 + r;
    slots[e] = cell;
    int old = atomicExch(&head[cell], e);
    BN bn; bn.w = b[r]; bn.next = old;
    bnext[e] = bn;
  }
}

// Phase 2: gather-splat per cell; writes zeros for empty cells (ws is poisoned)
__global__ void k_gather_d(const int* __restrict__ head,
                           const BN* __restrict__ bnext,
                           const float4* __restrict__ qp,
                           float* __restrict__ vals)
{
  int c = blockIdx.x * blockDim.x + threadIdx.x;
  if (c >= GCELLS1) return;
  int e = head[c];
  float s0 = 0.f, s1 = 0.f, s2 = 0.f, s3 = 0.f, s4 = 0.f;
  while (e >= 0){
    BN bn = bnext[e];
    float4 q = qp[e / 5];
    s0 += bn.w * q.x; s1 += bn.w * q.y; s2 += bn.w * q.z; s3 += bn.w * q.w; s4 += bn.w;
    e = bn.next;
  }
  float* v = vals + (size_t)c * 5;
  v[0] = s0; v[1] = s1; v[2] = s2; v[3] = s3; v[4] = s4;
}

// Phase 3: dense blur pass — neighbors are constant flat-index deltas
// (two cases keyed on r). Empty cells stay exactly zero.
__global__ void k_blur_d(const int* __restrict__ head,
                         const float* __restrict__ vin,
                         float* __restrict__ vout,
                         int dPa, int dPb, int dMa, int dMb)
{
  int c = blockIdx.x * blockDim.x + threadIdx.x;
  if (c >= GCELLS) return;
  float* vo = vout + (size_t)c * 5;
  if (head[c] < 0){
    vo[0] = 0.f; vo[1] = 0.f; vo[2] = 0.f; vo[3] = 0.f; vo[4] = 0.f;
    return;
  }
  int r = c % 5;
  int p1 = c + (r == 4 ? dPb : dPa);
  int p2 = c + (r == 0 ? dMb : dMa);
  const float* va = vin + (size_t)c * 5;
  const float* n1 = vin + (size_t)p1 * 5;  // empty neighbors hold zeros
  const float* n2 = vin + (size_t)p2 * 5;
  #pragma unroll
  for (int ch = 0; ch < 5; ch++)
    vo[ch] = 0.5f * va[ch] + 0.25f * (n1[ch] + n2[ch]);
}

// Phase 4: slice + normalize (direct cell addressing)
__global__ void k_slice_d(const int* __restrict__ slots,
                          const BN* __restrict__ bnext,
                          const float* __restrict__ vals,
                          float* __restrict__ out)
{
  int n = blockIdx.x * blockDim.x + threadIdx.x;
  if (n >= NPTS) return;
  float s0 = 0.f, s1 = 0.f, s2 = 0.f, s3 = 0.f, s4 = 0.f;
  #pragma unroll
  for (int r = 0; r < 5; r++){
    int e = n * 5 + r;
    int c = slots[e];
    float w = bnext[e].w;
    const float* v = vals + (size_t)c * 5;
    s0 += w * v[0]; s1 += w * v[1]; s2 += w * v[2]; s3 += w * v[3]; s4 += w * v[4];
  }
  float denom = s4 + 2.2204460492503131e-16f;
  out[n]            = s0 / denom;
  out[NPTS + n]     = s1 / denom;
  out[2 * NPTS + n] = s2 / denom;
  out[3 * NPTS + n] = s3 / denom;
}

// ============================ HASH FALLBACK PATH ============================

__global__ void k_build_h(const float* __restrict__ image,
                          unsigned long long* __restrict__ hkeys,
                          unsigned int tmask,
                          int* __restrict__ slots,
                          float* __restrict__ baryo,
                          int* __restrict__ head,
                          int* __restrict__ nexte,
                          int* __restrict__ hidx,
                          unsigned long long* __restrict__ lkeys,
                          int* __restrict__ lslot,
                          int* __restrict__ cnt,
                          int Mmax)
{
  int n = blockIdx.x * blockDim.x + threadIdx.x;
  if (n >= NPTS) return;
  LATTICE_MATH(n)

  #pragma unroll
  for (int r = 0; r < 5; r++){
    long long enc = 0;
    #pragma unroll
    for (int i = 0; i < 4; i++){
      int ki = rem0i[i] + (rank[i] < 5 - r ? r : r - 5);
      enc = enc * 8192 + (long long)(ki + 4096);
    }
    unsigned long long key = (unsigned long long)enc;
    unsigned int slot = (unsigned int)mix64(key) & tmask;
    bool won = false;
    while (true){
      unsigned long long k = hkeys[slot];
      if (k == key) break;
      if (k == EMPTY_KEY){
        unsigned long long prev = atomicCAS(&hkeys[slot], EMPTY_KEY, key);
        if (prev == EMPTY_KEY){ won = true; break; }
        if (prev == key) break;
      }
      slot = (slot + 1) & tmask;
    }
    if (won){
      int m = atomicAdd(cnt, 1);
      if (m < Mmax){ hidx[slot] = m; lkeys[m] = key; lslot[m] = (int)slot; }
    }
    int e = n * 5 + r;
    slots[e] = (int)slot;
    baryo[e] = b[r];
    int old = atomicExch(&head[slot], e);
    nexte[e] = old;
  }
}

__global__ void k_gather_h(const int* __restrict__ lslot,
                           const int* __restrict__ head,
                           const int* __restrict__ nexte,
                           const float* __restrict__ bary,
                           const float4* __restrict__ qp,
                           float* __restrict__ vals,
                           const int* __restrict__ counterM, int Mmax)
{
  int m = blockIdx.x * blockDim.x + threadIdx.x;
  int M = *counterM; if (M > Mmax) M = Mmax;
  if (m >= M) return;
  int e = head[lslot[m]];
  float s0 = 0.f, s1 = 0.f, s2 = 0.f, s3 = 0.f, s4 = 0.f;
  while (e >= 0){
    float w = bary[e];
    float4 q = qp[e / 5];
    s0 += w * q.x; s1 += w * q.y; s2 += w * q.z; s3 += w * q.w; s4 += w;
    e = nexte[e];
  }
  float* v = vals + (size_t)m * 5;
  v[0] = s0; v[1] = s1; v[2] = s2; v[3] = s3; v[4] = s4;
}

__global__ void k_blur_h(const unsigned long long* __restrict__ hkeys,
                         const int* __restrict__ hidx,
                         const unsigned long long* __restrict__ lkeys,
                         const float* __restrict__ vin,
                         float* __restrict__ vout,
                         const int* __restrict__ counterM,
                         unsigned int tmask, long long delta, int Mmax)
{
  int m = blockIdx.x * blockDim.x + threadIdx.x;
  int M = *counterM; if (M > Mmax) M = Mmax;
  if (m >= M) return;
  unsigned long long key = lkeys[m];
  int p1 = hfind(hkeys, hidx, (unsigned long long)((long long)key + delta), tmask);
  int p2 = hfind(hkeys, hidx, (unsigned long long)((long long)key - delta), tmask);
  #pragma unroll
  for (int c = 0; c < 5; c++){
    float n1 = (p1 >= 0) ? vin[p1 * 5 + c] : 0.0f;
    float n2 = (p2 >= 0) ? vin[p2 * 5 + c] : 0.0f;
    vout[m * 5 + c] = 0.5f * vin[m * 5 + c] + 0.25f * (n1 + n2);
  }
}

__global__ void k_slice_h(const int* __restrict__ slots,
                          const float* __restrict__ bary,
                          const int* __restrict__ hidx,
                          const float* __restrict__ vals,
                          float* __restrict__ out,
                          const int* __restrict__ counterM, int Mmax)
{
  int n = blockIdx.x * blockDim.x + threadIdx.x;
  if (n >= NPTS) return;
  int Mact = *counterM; if (Mact > Mmax) Mact = Mmax;
  float s[5] = {0.f,0.f,0.f,0.f,0.f};
  #pragma unroll
  for (int r = 0; r < 5; r++){
    int m = hidx[slots[n * 5 + r]];
    float w = bary[n * 5 + r];
    if (m >= 0 && m < Mact){
      #pragma unroll
      for (int c = 0; c < 5; c++) s[c] += w * vals[m * 5 + c];
    }
  }
  float denom = s[4] + 2.2204460492503131e-16f;
  #pragma unroll
  for (int c = 0; c < 4; c++) out[c * NPTS + n] = s[c] / denom;
}

// ============================ HOST ============================

extern "C" void kernel_launch(void* const* d_in, const int* in_sizes, int n_in,
                              void* d_out, int out_size, void* d_ws, size_t ws_size,
                              hipStream_t stream)
{
  const float* input_ = (const float*)d_in[0];
  const float* image  = (const float*)d_in[1];
  float* out = (float*)d_out;
  char* ws = (char*)d_ws;

  const int NB = (NPTS + 255) / 256;

  // ---- Dense-grid path workspace ----
  size_t o = 0;
  size_t off_head  = o; o += (size_t)GCELLS1 * 4;      o = (o + 255) & ~(size_t)255;
  size_t off_slots = o; o += (size_t)NP5 * 4;          o = (o + 255) & ~(size_t)255;
  size_t off_bnext = o; o += (size_t)NP5 * 8;          o = (o + 255) & ~(size_t)255;
  size_t off_qp    = o; o += (size_t)NPTS * 16;        o = (o + 255) & ~(size_t)255;
  size_t off_vA    = o; o += (size_t)GCELLS1 * 5 * 4;  o = (o + 255) & ~(size_t)255;
  size_t off_vB    = o; o += (size_t)GCELLS1 * 5 * 4;
  const size_t dense_need = o;

  if (dense_need <= ws_size){
    int*    head  = (int*)(ws + off_head);
    int*    slots = (int*)(ws + off_slots);
    BN*     bnext = (BN*)(ws + off_bnext);
    float4* qp    = (float4*)(ws + off_qp);
    float*  valsA = (float*)(ws + off_vA);
    float*  valsB = (float*)(ws + off_vB);

    hipMemsetAsync(head, 0xFF, (size_t)GCELLS1 * 4, stream);

    k_qpack<<<NB, 256, 0, stream>>>(input_, qp);
    k_build_d<<<NB, 256, 0, stream>>>(image, head, slots, bnext);

    const int CB = (GCELLS1 + 255) / 256;
    k_gather_d<<<CB, 256, 0, stream>>>(head, bnext, qp, valsA);

    const int Sj[5] = { GS0, GS1, GS2, GS3, 0 };
    float* vin = valsA; float* vout = valsB;
    for (int j = 0; j < 5; j++){
      int dPa = 1 - Sj[j];
      int dPb = GSSUM - Sj[j] - 4;
      int dMa = Sj[j] - 1;
      int dMb = Sj[j] - GSSUM + 4;
      k_blur_d<<<CB, 256, 0, stream>>>(head, vin, vout, dPa, dPb, dMa, dMb);
      float* t = vin; vin = vout; vout = t;
    }

    k_slice_d<<<NB, 256, 0, stream>>>(slots, bnext, vin, out);
    return;
  }

  // ---- Hash fallback path ----
  struct Cfg { int tb; size_t M; };
  const Cfg cfgs[] = {
    {23, (size_t)NP5}, {23, 3200000}, {22, 2000000}, {21, 1500000}, {20, 1000000}
  };
  const int NCFG = sizeof(cfgs) / sizeof(cfgs[0]);

  int tbits = 20; size_t Mmax = 1000000;
  size_t off_hkeys = 0, off_hidx = 0, off_head2 = 0, off_cnt = 0, off_slots2 = 0,
         off_bary = 0, off_next = 0, off_lkeys = 0, off_lslot = 0, off_qp2 = 0,
         off_vA2 = 0, off_vB2 = 0;
  for (int i = 0; i < NCFG; i++){
    size_t T = (size_t)1 << cfgs[i].tb; size_t M = cfgs[i].M;
    size_t oo = 0;
    off_hkeys = oo; oo += T * 8;
    off_hidx  = oo; oo += T * 4;
    off_head2 = oo; oo += T * 4;
    off_cnt   = oo; oo += 256;
    off_slots2= oo; oo += (size_t)NP5 * 4;
    off_bary  = oo; oo += (size_t)NP5 * 4;
    off_next  = oo; oo += (size_t)NP5 * 4;
    off_lkeys = oo; oo += M * 8;
    off_lslot = oo; oo += M * 4;
    off_qp2   = oo; oo += (size_t)NPTS * 16;
    off_vA2   = oo; oo += M * 5 * 4;
    off_vB2   = oo; oo += M * 5 * 4;
    tbits = cfgs[i].tb; Mmax = M;
    if (oo <= ws_size) break;
  }
  size_t T = (size_t)1 << tbits;
  unsigned int tmask = (unsigned int)(T - 1);

  unsigned long long* hkeys = (unsigned long long*)(ws + off_hkeys);
  int*                hidx  = (int*)(ws + off_hidx);
  int*                head  = (int*)(ws + off_head2);
  int*                cnt   = (int*)(ws + off_cnt);
  int*                slots = (int*)(ws + off_slots2);
  float*              bary  = (float*)(ws + off_bary);
  int*                nexte = (int*)(ws + off_next);
  unsigned long long* lkeys = (unsigned long long*)(ws + off_lkeys);
  int*                lslot = (int*)(ws + off_lslot);
  float4*             qp    = (float4*)(ws + off_qp2);
  float*              valsA = (float*)(ws + off_vA2);
  float*              valsB = (float*)(ws + off_vB2);

  hipMemsetAsync(ws + off_hkeys, 0xFF, T * 8 + T * 4 + T * 4, stream);
  hipMemsetAsync(ws + off_cnt, 0, 256, stream);

  const int MB = (int)((Mmax + 255) / 256);

  k_qpack<<<NB, 256, 0, stream>>>(input_, qp);
  k_build_h<<<NB, 256, 0, stream>>>(image, hkeys, tmask, slots, bary, head, nexte,
                                    hidx, lkeys, lslot, cnt, (int)Mmax);
  k_gather_h<<<MB, 256, 0, stream>>>(lslot, head, nexte, bary, qp, valsA, cnt, (int)Mmax);

  const long long P3 = 1ll << 39, P2 = 1ll << 26, P1 = 1ll << 13, P0 = 1ll;
  const long long Dall = P3 + P2 + P1 + P0;
  const long long deltas[5] = { Dall - 5*P3, Dall - 5*P2, Dall - 5*P1, Dall - 5*P0, Dall };

  float* vin = valsA; float* vout = valsB;
  for (int j = 0; j < 5; j++){
    k_blur_h<<<MB, 256, 0, stream>>>(hkeys, hidx, lkeys, vin, vout, cnt, tmask, deltas[j], (int)Mmax);
    float* t = vin; vin = vout; vout = t;
  }

  k_slice_h<<<NB, 256, 0, stream>>>(slots, bary, hidx, vin, out, cnt, (int)Mmax);
}

// Round 6
// 458.437 us; speedup vs baseline: 4.4452x; 1.0875x over previous
//
#include <hip/hip_runtime.h>
#include <stdint.h>

#define NPTS (96*96*96)          // 884736
#define NP5  (NPTS*5)            // 4423680 entries (point,vertex)
#define EMPTY_KEY 0xFFFFFFFFFFFFFFFFull

// Dense lattice grid (derived via interval arithmetic from the fixed input
// domain: z,y,x in [0,95], image in [0,1); includes rank-adjust, r-offset,
// blur-neighbor padding, and +/-2 safety margin):
//   q0 in [-3,25], q1 in [-14,14], q2 in [-16,8], q3 in [-17,3]
#define GD1 33
#define GD2 29
#define GD3 25
#define GO0 5
#define GO1 16
#define GO2 18
#define GO3 19
#define GS3 5
#define GS2 (GD3*GS3)      // 125
#define GS1 (GD2*GS2)      // 3625
#define GS0 (GD1*GS1)      // 119625
#define GCELLS (31*GS0)    // 3708375
#define GCELLS1 (GCELLS+1) // + trash cell for (never-expected) OOB
#define GSSUM (GS0+GS1+GS2+GS3)  // 123380

struct BN { float w; int next; };   // bary weight + chain link, 8B

__device__ __forceinline__ uint64_t mix64(uint64_t x){
  x ^= x >> 33; x *= 0xff51afd7ed558ccdULL;
  x ^= x >> 33; x *= 0xc4ceb9fe1a85ec53ULL;
  x ^= x >> 33; return x;
}

__device__ __forceinline__ int hfind(const unsigned long long* __restrict__ hkeys,
                                     const int* __restrict__ hidx,
                                     unsigned long long key, unsigned int tmask){
  unsigned int slot = (unsigned int)mix64(key) & tmask;
  while (true){
    unsigned long long k = hkeys[slot];
    if (k == key) return hidx[slot];
    if (k == EMPTY_KEY) return -1;
    slot = (slot + 1) & tmask;
  }
}

// Pack input_ channels into float4 per point
__global__ void k_qpack(const float* __restrict__ input_, float4* __restrict__ qp)
{
  int n = blockIdx.x * blockDim.x + threadIdx.x;
  if (n >= NPTS) return;
  qp[n] = make_float4(input_[n], input_[NPTS + n], input_[2 * NPTS + n], input_[3 * NPTS + n]);
}

// Shared per-point lattice math macro producing rank[5], rem0i[4], b[]
#define LATTICE_MATH(n)                                                        \
  int x = n % 96, y = (n / 96) % 96, z = n / (96 * 96);                        \
  float cf[4];                                                                 \
  cf[0] = ((float)z / 5.0f) * 2.8867513459481287f;                             \
  cf[1] = ((float)y / 5.0f) * 1.6666666666666667f;                             \
  cf[2] = ((float)x / 5.0f) * 1.1785113019775793f;                             \
  cf[3] = (image[n] / 0.25f) * 0.9128709291752769f;                            \
  float elev[5];                                                               \
  float sm = 0.f;                                                              \
  _Pragma("unroll")                                                            \
  for (int i = 4; i >= 1; --i){ float c = cf[i-1]; elev[i] = sm - (float)i * c; sm += c; } \
  elev[0] = sm;                                                                \
  float rem0[5]; float sumrd_f = 0.f;                                          \
  _Pragma("unroll")                                                            \
  for (int i = 0; i < 5; i++){ float rd = rintf(elev[i] / 5.0f); rem0[i] = rd * 5.0f; sumrd_f += rd; } \
  int sum_rd = (int)sumrd_f;                                                   \
  float diff[5];                                                               \
  _Pragma("unroll")                                                            \
  for (int i = 0; i < 5; i++) diff[i] = elev[i] - rem0[i];                     \
  int rank[5];                                                                 \
  _Pragma("unroll")                                                            \
  for (int i = 0; i < 5; i++){                                                 \
    int r = 0;                                                                 \
    _Pragma("unroll")                                                          \
    for (int j = 0; j < 5; j++){                                               \
      r += (diff[j] > diff[i] || (diff[j] == diff[i] && j < i)) ? 1 : 0;       \
    }                                                                          \
    rank[i] = r + sum_rd;                                                      \
  }                                                                            \
  _Pragma("unroll")                                                            \
  for (int i = 0; i < 5; i++){                                                 \
    if (rank[i] < 0)      { rank[i] += 5; rem0[i] += 5.0f; }                   \
    else if (rank[i] > 4) { rank[i] -= 5; rem0[i] -= 5.0f; }                   \
  }                                                                            \
  float b[6] = {0.f,0.f,0.f,0.f,0.f,0.f};                                      \
  _Pragma("unroll")                                                            \
  for (int i = 0; i < 5; i++){                                                 \
    float v = (elev[i] - rem0[i]) / 5.0f;                                      \
    b[4 - rank[i]] += v;                                                       \
    b[5 - rank[i]] -= v;                                                       \
  }                                                                            \
  b[0] += 1.0f + b[5];                                                         \
  int rem0i[4];                                                                \
  _Pragma("unroll")                                                            \
  for (int i = 0; i < 4; i++) rem0i[i] = (int)rem0[i];

// Cell index for vertex r (shared by build & slice — must stay identical)
#define CELL_OF_R(r, cell)                                                     \
  int q0 = (rem0i[0] / 5) - (rank[0] < 5 - (r) ? 0 : 1) + GO0;                 \
  int q1 = (rem0i[1] / 5) - (rank[1] < 5 - (r) ? 0 : 1) + GO1;                 \
  int q2 = (rem0i[2] / 5) - (rank[2] < 5 - (r) ? 0 : 1) + GO2;                 \
  int q3 = (rem0i[3] / 5) - (rank[3] < 5 - (r) ? 0 : 1) + GO3;                 \
  int cell = (((q0 * GD1 + q1) * GD2 + q2) * GD3 + q3) * 5 + (r);              \
  if ((unsigned)cell >= (unsigned)GCELLS) cell = GCELLS;

// ============================ DENSE-GRID PATH ============================

// Phase 1: lattice math + direct cell addressing + chain inversion (exch only)
__global__ void k_build_d(const float* __restrict__ image,
                          int* __restrict__ head,
                          BN* __restrict__ bnext)
{
  int n = blockIdx.x * blockDim.x + threadIdx.x;
  if (n >= NPTS) return;
  LATTICE_MATH(n)

  #pragma unroll
  for (int r = 0; r < 5; r++){
    CELL_OF_R(r, cell)
    int e = n * 5 + r;
    int old = atomicExch(&head[cell], e);
    BN bn; bn.w = b[r]; bn.next = old;
    bnext[e] = bn;
  }
}

// Phase 2: gather-splat per cell; writes zeros for empty cells; also emits
// the occupancy bitmap via wave ballot (zero atomics).
__global__ void k_gather_d(const int* __restrict__ head,
                           const BN* __restrict__ bnext,
                           const float4* __restrict__ qp,
                           float* __restrict__ vals,
                           unsigned int* __restrict__ bitmap)
{
  int c = blockIdx.x * blockDim.x + threadIdx.x;
  int e = -1;
  if (c < GCELLS1) e = head[c];
  bool occ = (e >= 0);
  unsigned long long mask = __ballot(occ);
  int lane = threadIdx.x & 63;
  if (lane == 0)       bitmap[c >> 5] = (unsigned int)(mask & 0xffffffffu);
  else if (lane == 32) bitmap[c >> 5] = (unsigned int)(mask >> 32);
  if (c >= GCELLS1) return;

  float s0 = 0.f, s1 = 0.f, s2 = 0.f, s3 = 0.f, s4 = 0.f;
  while (e >= 0){
    BN bn = bnext[e];
    float4 q = qp[e / 5];
    s0 += bn.w * q.x; s1 += bn.w * q.y; s2 += bn.w * q.z; s3 += bn.w * q.w; s4 += bn.w;
    e = bn.next;
  }
  float* v = vals + (size_t)c * 5;
  v[0] = s0; v[1] = s1; v[2] = s2; v[3] = s3; v[4] = s4;
}

// Phase 3: dense blur pass — neighbors are constant flat-index deltas.
// Empty cells: zfill=1 (pass 1) writes zeros into the poisoned buffer;
// zfill=0 (passes >=2) skips the store — ping-pong invariant guarantees the
// target buffer's empties were zeroed two passes earlier.
__global__ void k_blur_d(const unsigned int* __restrict__ bitmap,
                         const float* __restrict__ vin,
                         float* __restrict__ vout,
                         int dPa, int dPb, int dMa, int dMb, int zfill)
{
  int c = blockIdx.x * blockDim.x + threadIdx.x;
  if (c >= GCELLS) return;
  unsigned int w = bitmap[c >> 5];
  if (!((w >> (c & 31)) & 1u)){
    if (zfill){
      float* vo = vout + (size_t)c * 5;
      vo[0] = 0.f; vo[1] = 0.f; vo[2] = 0.f; vo[3] = 0.f; vo[4] = 0.f;
    }
    return;
  }
  int r = c % 5;
  int p1 = c + (r == 4 ? dPb : dPa);
  int p2 = c + (r == 0 ? dMb : dMa);
  float* vo = vout + (size_t)c * 5;
  const float* va = vin + (size_t)c * 5;
  const float* n1 = vin + (size_t)p1 * 5;  // empty neighbors hold zeros
  const float* n2 = vin + (size_t)p2 * 5;
  #pragma unroll
  for (int ch = 0; ch < 5; ch++)
    vo[ch] = 0.5f * va[ch] + 0.25f * (n1[ch] + n2[ch]);
}

// Phase 4: slice + normalize — recomputes cells & weights (bit-identical to
// build) instead of loading slots/bary arrays.
__global__ void k_slice_d(const float* __restrict__ image,
                          const float* __restrict__ vals,
                          float* __restrict__ out)
{
  int n = blockIdx.x * blockDim.x + threadIdx.x;
  if (n >= NPTS) return;
  LATTICE_MATH(n)

  float s0 = 0.f, s1 = 0.f, s2 = 0.f, s3 = 0.f, s4 = 0.f;
  #pragma unroll
  for (int r = 0; r < 5; r++){
    CELL_OF_R(r, cell)
    float w = b[r];
    const float* v = vals + (size_t)cell * 5;
    s0 += w * v[0]; s1 += w * v[1]; s2 += w * v[2]; s3 += w * v[3]; s4 += w * v[4];
  }
  float denom = s4 + 2.2204460492503131e-16f;
  out[n]            = s0 / denom;
  out[NPTS + n]     = s1 / denom;
  out[2 * NPTS + n] = s2 / denom;
  out[3 * NPTS + n] = s3 / denom;
}

// ============================ HASH FALLBACK PATH ============================

__global__ void k_build_h(const float* __restrict__ image,
                          unsigned long long* __restrict__ hkeys,
                          unsigned int tmask,
                          int* __restrict__ slots,
                          float* __restrict__ baryo,
                          int* __restrict__ head,
                          int* __restrict__ nexte,
                          int* __restrict__ hidx,
                          unsigned long long* __restrict__ lkeys,
                          int* __restrict__ lslot,
                          int* __restrict__ cnt,
                          int Mmax)
{
  int n = blockIdx.x * blockDim.x + threadIdx.x;
  if (n >= NPTS) return;
  LATTICE_MATH(n)

  #pragma unroll
  for (int r = 0; r < 5; r++){
    long long enc = 0;
    #pragma unroll
    for (int i = 0; i < 4; i++){
      int ki = rem0i[i] + (rank[i] < 5 - r ? r : r - 5);
      enc = enc * 8192 + (long long)(ki + 4096);
    }
    unsigned long long key = (unsigned long long)enc;
    unsigned int slot = (unsigned int)mix64(key) & tmask;
    bool won = false;
    while (true){
      unsigned long long k = hkeys[slot];
      if (k == key) break;
      if (k == EMPTY_KEY){
        unsigned long long prev = atomicCAS(&hkeys[slot], EMPTY_KEY, key);
        if (prev == EMPTY_KEY){ won = true; break; }
        if (prev == key) break;
      }
      slot = (slot + 1) & tmask;
    }
    if (won){
      int m = atomicAdd(cnt, 1);
      if (m < Mmax){ hidx[slot] = m; lkeys[m] = key; lslot[m] = (int)slot; }
    }
    int e = n * 5 + r;
    slots[e] = (int)slot;
    baryo[e] = b[r];
    int old = atomicExch(&head[slot], e);
    nexte[e] = old;
  }
}

__global__ void k_gather_h(const int* __restrict__ lslot,
                           const int* __restrict__ head,
                           const int* __restrict__ nexte,
                           const float* __restrict__ bary,
                           const float4* __restrict__ qp,
                           float* __restrict__ vals,
                           const int* __restrict__ counterM, int Mmax)
{
  int m = blockIdx.x * blockDim.x + threadIdx.x;
  int M = *counterM; if (M > Mmax) M = Mmax;
  if (m >= M) return;
  int e = head[lslot[m]];
  float s0 = 0.f, s1 = 0.f, s2 = 0.f, s3 = 0.f, s4 = 0.f;
  while (e >= 0){
    float w = bary[e];
    float4 q = qp[e / 5];
    s0 += w * q.x; s1 += w * q.y; s2 += w * q.z; s3 += w * q.w; s4 += w;
    e = nexte[e];
  }
  float* v = vals + (size_t)m * 5;
  v[0] = s0; v[1] = s1; v[2] = s2; v[3] = s3; v[4] = s4;
}

__global__ void k_blur_h(const unsigned long long* __restrict__ hkeys,
                         const int* __restrict__ hidx,
                         const unsigned long long* __restrict__ lkeys,
                         const float* __restrict__ vin,
                         float* __restrict__ vout,
                         const int* __restrict__ counterM,
                         unsigned int tmask, long long delta, int Mmax)
{
  int m = blockIdx.x * blockDim.x + threadIdx.x;
  int M = *counterM; if (M > Mmax) M = Mmax;
  if (m >= M) return;
  unsigned long long key = lkeys[m];
  int p1 = hfind(hkeys, hidx, (unsigned long long)((long long)key + delta), tmask);
  int p2 = hfind(hkeys, hidx, (unsigned long long)((long long)key - delta), tmask);
  #pragma unroll
  for (int c = 0; c < 5; c++){
    float n1 = (p1 >= 0) ? vin[p1 * 5 + c] : 0.0f;
    float n2 = (p2 >= 0) ? vin[p2 * 5 + c] : 0.0f;
    vout[m * 5 + c] = 0.5f * vin[m * 5 + c] + 0.25f * (n1 + n2);
  }
}

__global__ void k_slice_h(const int* __restrict__ slots,
                          const float* __restrict__ bary,
                          const int* __restrict__ hidx,
                          const float* __restrict__ vals,
                          float* __restrict__ out,
                          const int* __restrict__ counterM, int Mmax)
{
  int n = blockIdx.x * blockDim.x + threadIdx.x;
  if (n >= NPTS) return;
  int Mact = *counterM; if (Mact > Mmax) Mact = Mmax;
  float s[5] = {0.f,0.f,0.f,0.f,0.f};
  #pragma unroll
  for (int r = 0; r < 5; r++){
    int m = hidx[slots[n * 5 + r]];
    float w = bary[n * 5 + r];
    if (m >= 0 && m < Mact){
      #pragma unroll
      for (int c = 0; c < 5; c++) s[c] += w * vals[m * 5 + c];
    }
  }
  float denom = s[4] + 2.2204460492503131e-16f;
  #pragma unroll
  for (int c = 0; c < 4; c++) out[c * NPTS + n] = s[c] / denom;
}

// ============================ HOST ============================

extern "C" void kernel_launch(void* const* d_in, const int* in_sizes, int n_in,
                              void* d_out, int out_size, void* d_ws, size_t ws_size,
                              hipStream_t stream)
{
  const float* input_ = (const float*)d_in[0];
  const float* image  = (const float*)d_in[1];
  float* out = (float*)d_out;
  char* ws = (char*)d_ws;

  const int NB = (NPTS + 255) / 256;
  const int CB = (GCELLS1 + 255) / 256;
  const size_t BMWORDS = (size_t)CB * 8;   // 32 cells/word, covers CB*256 cells

  // ---- Dense-grid path workspace ----
  size_t o = 0;
  size_t off_head  = o; o += (size_t)GCELLS1 * 4;      o = (o + 255) & ~(size_t)255;
  size_t off_bm    = o; o += BMWORDS * 4;              o = (o + 255) & ~(size_t)255;
  size_t off_bnext = o; o += (size_t)NP5 * 8;          o = (o + 255) & ~(size_t)255;
  size_t off_qp    = o; o += (size_t)NPTS * 16;        o = (o + 255) & ~(size_t)255;
  size_t off_vA    = o; o += (size_t)GCELLS1 * 5 * 4;  o = (o + 255) & ~(size_t)255;
  size_t off_vB    = o; o += (size_t)GCELLS1 * 5 * 4;
  const size_t dense_need = o;

  if (dense_need <= ws_size){
    int*          head   = (int*)(ws + off_head);
    unsigned int* bitmap = (unsigned int*)(ws + off_bm);
    BN*           bnext  = (BN*)(ws + off_bnext);
    float4*       qp     = (float4*)(ws + off_qp);
    float*        valsA  = (float*)(ws + off_vA);
    float*        valsB  = (float*)(ws + off_vB);

    hipMemsetAsync(head, 0xFF, (size_t)GCELLS1 * 4, stream);

    k_qpack<<<NB, 256, 0, stream>>>(input_, qp);
    k_build_d<<<NB, 256, 0, stream>>>(image, head, bnext);
    k_gather_d<<<CB, 256, 0, stream>>>(head, bnext, qp, valsA, bitmap);

    const int Sj[5] = { GS0, GS1, GS2, GS3, 0 };
    float* vin = valsA; float* vout = valsB;
    for (int j = 0; j < 5; j++){
      int dPa = 1 - Sj[j];
      int dPb = GSSUM - Sj[j] - 4;
      int dMa = Sj[j] - 1;
      int dMb = Sj[j] - GSSUM + 4;
      k_blur_d<<<CB, 256, 0, stream>>>(bitmap, vin, vout, dPa, dPb, dMa, dMb,
                                       (j == 0) ? 1 : 0);
      float* t = vin; vin = vout; vout = t;
    }

    k_slice_d<<<NB, 256, 0, stream>>>(image, vin, out);
    return;
  }

  // ---- Hash fallback path ----
  struct Cfg { int tb; size_t M; };
  const Cfg cfgs[] = {
    {23, (size_t)NP5}, {23, 3200000}, {22, 2000000}, {21, 1500000}, {20, 1000000}
  };
  const int NCFG = sizeof(cfgs) / sizeof(cfgs[0]);

  int tbits = 20; size_t Mmax = 1000000;
  size_t off_hkeys = 0, off_hidx = 0, off_head2 = 0, off_cnt = 0, off_slots2 = 0,
         off_bary = 0, off_next = 0, off_lkeys = 0, off_lslot = 0, off_qp2 = 0,
         off_vA2 = 0, off_vB2 = 0;
  for (int i = 0; i < NCFG; i++){
    size_t T = (size_t)1 << cfgs[i].tb; size_t M = cfgs[i].M;
    size_t oo = 0;
    off_hkeys = oo; oo += T * 8;
    off_hidx  = oo; oo += T * 4;
    off_head2 = oo; oo += T * 4;
    off_cnt   = oo; oo += 256;
    off_slots2= oo; oo += (size_t)NP5 * 4;
    off_bary  = oo; oo += (size_t)NP5 * 4;
    off_next  = oo; oo += (size_t)NP5 * 4;
    off_lkeys = oo; oo += M * 8;
    off_lslot = oo; oo += M * 4;
    off_qp2   = oo; oo += (size_t)NPTS * 16;
    off_vA2   = oo; oo += M * 5 * 4;
    off_vB2   = oo; oo += M * 5 * 4;
    tbits = cfgs[i].tb; Mmax = M;
    if (oo <= ws_size) break;
  }
  size_t T = (size_t)1 << tbits;
  unsigned int tmask = (unsigned int)(T - 1);

  unsigned long long* hkeys = (unsigned long long*)(ws + off_hkeys);
  int*                hidx  = (int*)(ws + off_hidx);
  int*                head  = (int*)(ws + off_head2);
  int*                cnt   = (int*)(ws + off_cnt);
  int*                slots = (int*)(ws + off_slots2);
  float*              bary  = (float*)(ws + off_bary);
  int*                nexte = (int*)(ws + off_next);
  unsigned long long* lkeys = (unsigned long long*)(ws + off_lkeys);
  int*                lslot = (int*)(ws + off_lslot);
  float4*             qp    = (float4*)(ws + off_qp2);
  float*              valsA = (float*)(ws + off_vA2);
  float*              valsB = (float*)(ws + off_vB2);

  hipMemsetAsync(ws + off_hkeys, 0xFF, T * 8 + T * 4 + T * 4, stream);
  hipMemsetAsync(ws + off_cnt, 0, 256, stream);

  const int MB = (int)((Mmax + 255) / 256);

  k_qpack<<<NB, 256, 0, stream>>>(input_, qp);
  k_build_h<<<NB, 256, 0, stream>>>(image, hkeys, tmask, slots, bary, head, nexte,
                                    hidx, lkeys, lslot, cnt, (int)Mmax);
  k_gather_h<<<MB, 256, 0, stream>>>(lslot, head, nexte, bary, qp, valsA, cnt, (int)Mmax);

  const long long P3 = 1ll << 39, P2 = 1ll << 26, P1 = 1ll << 13, P0 = 1ll;
  const long long Dall = P3 + P2 + P1 + P0;
  const long long deltas[5] = { Dall - 5*P3, Dall - 5*P2, Dall - 5*P1, Dall - 5*P0, Dall };

  float* vin = valsA; float* vout = valsB;
  for (int j = 0; j < 5; j++){
    k_blur_h<<<MB, 256, 0, stream>>>(hkeys, hidx, lkeys, vin, vout, cnt, tmask, deltas[j], (int)Mmax);
    float* t = vin; vin = vout; vout = t;
  }

  k_slice_h<<<NB, 256, 0, stream>>>(slots, bary, hidx, vin, out, cnt, (int)Mmax);
}